// Round 1
// baseline (584.966 us; speedup 1.0000x reference)
//
#include <hip/hip_runtime.h>
#include <stdint.h>

typedef unsigned long long u64;

#define C_SIZE 32768
#define N_SIZE 900
#define B_SIZE 128
#define NWORDS 15      // ceil(900/64): 14 full words + 4 bits
#define WSTRIDE 16     // padded row stride in u64 (128 B, aligned)
#define NBUCKETS 901   // d in [0, 900]

// ---------------------------------------------------------------------------
// Kernel A: pack 0/1 float rows into bitmasks, one wave per row.
// Wave reads 64 consecutive floats, __ballot(v != 0) gives the 64-bit word.
// Lanes 0..15 then store the 16-word (padded) row coalesced (128 B).
// ---------------------------------------------------------------------------
__global__ __launch_bounds__(256) void pack_bits(const float* __restrict__ src,
                                                 u64* __restrict__ dst, int rows) {
    int wave = (int)((blockIdx.x * blockDim.x + threadIdx.x) >> 6);
    int lane = (int)(threadIdx.x & 63);
    if (wave >= rows) return;
    const float* row = src + (size_t)wave * N_SIZE;
    u64 myword = 0;
#pragma unroll
    for (int w = 0; w < NWORDS; ++w) {
        int j = w * 64 + lane;
        float v = 0.0f;
        if (j < N_SIZE) v = row[j];
        u64 m = __ballot(v != 0.0f);
        if (lane == w) myword = m;
    }
    if (lane < WSTRIDE) dst[(size_t)wave * WSTRIDE + lane] = myword;
}

// ---------------------------------------------------------------------------
// Kernel B: for each cache row k, compute d(item) = popcount(row & y_true[item])
// for all 128 items (row bits held in registers), atomicMin row index into
// the (item, d) bucket. y_true bitmasks staged in LDS (15 KiB, broadcast reads).
// ---------------------------------------------------------------------------
__global__ __launch_bounds__(256) void compute_rep(const u64* __restrict__ cbits,
                                                   const u64* __restrict__ ybits,
                                                   int* __restrict__ rep) {
    __shared__ u64 yt[B_SIZE][NWORDS];
    for (int idx = threadIdx.x; idx < B_SIZE * NWORDS; idx += blockDim.x) {
        int it = idx / NWORDS, w = idx % NWORDS;
        yt[it][w] = ybits[(size_t)it * WSTRIDE + w];
    }
    __syncthreads();

    int k = (int)(blockIdx.x * blockDim.x + threadIdx.x);
    if (k >= C_SIZE) return;

    u64 ck[NWORDS];
#pragma unroll
    for (int w = 0; w < NWORDS; ++w) ck[w] = cbits[(size_t)k * WSTRIDE + w];

    for (int it = 0; it < B_SIZE; ++it) {
        int d = 0;
#pragma unroll
        for (int w = 0; w < NWORDS; ++w) d += (int)__popcll(ck[w] & yt[it][w]);
        atomicMin(&rep[it * NBUCKETS + d], k);
    }
}

// ---------------------------------------------------------------------------
// Kernel C: masked-sum dot s[rep] = sum_{j: cache[rep][j]==1} y_hat[item][j].
// One wave per (item, bucket t); bucket skipped if empty. Uses packed bits
// (broadcast word load) + y_hat (L1/L2 resident, 3.6 KB/item).
// ---------------------------------------------------------------------------
__global__ __launch_bounds__(256) void gather_s(const u64* __restrict__ cbits,
                                                const float* __restrict__ y_hat,
                                                const int* __restrict__ rep,
                                                float* __restrict__ svals) {
    int item = (int)blockIdx.y;
    int wave_in_item = (int)(blockIdx.x * (blockDim.x >> 6) + (threadIdx.x >> 6)); // 0..63
    int lane = (int)(threadIdx.x & 63);
    const float* yh = y_hat + (size_t)item * N_SIZE;

    for (int t = wave_in_item; t < NBUCKETS; t += 64) {
        int k = rep[item * NBUCKETS + t];   // wave-uniform
        if (k >= C_SIZE) continue;          // empty bucket
        float s = 0.0f;
#pragma unroll
        for (int w = 0; w < NWORDS; ++w) {
            u64 word = cbits[(size_t)k * WSTRIDE + w]; // broadcast
            int j = w * 64 + lane;
            if (j < N_SIZE && ((word >> lane) & 1ull)) s += yh[j];
        }
#pragma unroll
        for (int off = 32; off; off >>= 1) s += __shfl_xor(s, off, 64);
        if (lane == 0) svals[item * NBUCKETS + t] = s;
    }
}

// ---------------------------------------------------------------------------
// Kernel D: per item, find t_max (max present d), best = s[t_max],
// loss = sum_{present t < t_max} relu(s[t]-best) / max(cnt,1); mean over items.
// One block of 128 threads, LDS tree reduce.
// ---------------------------------------------------------------------------
__global__ void finalize(const int* __restrict__ rep, const float* __restrict__ svals,
                         float* __restrict__ out) {
    __shared__ float red[B_SIZE];
    int i = (int)threadIdx.x; // 0..127
    const int* r = rep + i * NBUCKETS;
    const float* s = svals + i * NBUCKETS;

    int tmax = -1;
    for (int t = NBUCKETS - 1; t >= 0; --t) {
        if (r[t] < C_SIZE) { tmax = t; break; }
    }
    float loss = 0.0f;
    if (tmax >= 0) {
        float best = s[tmax];
        float sum = 0.0f;
        int cnt = 0;
        for (int t = 0; t < tmax; ++t) {
            if (r[t] < C_SIZE) {
                float dd = s[t] - best;
                sum += (dd > 0.0f) ? dd : 0.0f;
                ++cnt;
            }
        }
        loss = sum / (float)((cnt > 1) ? cnt : 1);
    }
    red[i] = loss;
    __syncthreads();
    for (int off = 64; off; off >>= 1) {
        if (i < off) red[i] += red[i + off];
        __syncthreads();
    }
    if (i == 0) out[0] = red[0] / (float)B_SIZE;
}

extern "C" void kernel_launch(void* const* d_in, const int* in_sizes, int n_in,
                              void* d_out, int out_size, void* d_ws, size_t ws_size,
                              hipStream_t stream) {
    const float* y_hat  = (const float*)d_in[0];  // [128, 900]
    const float* y_true = (const float*)d_in[1];  // [128, 900] 0/1
    // d_in[2] = sol_true (unused)
    const float* cache  = (const float*)d_in[3];  // [32768, 900] 0/1

    char* ws = (char*)d_ws;
    u64*   cbits = (u64*)ws;                                   // 4 MiB
    u64*   ybits = (u64*)(ws + 4u * 1024 * 1024);              // 16 KiB
    int*   rep   = (int*)(ws + 4u * 1024 * 1024 + 64 * 1024);  // 461 KiB
    float* svals = (float*)(ws + 4u * 1024 * 1024 + 64 * 1024 + 512 * 1024); // 461 KiB

    // re-init rep buckets each call (0x7F7F7F7F > C_SIZE)
    hipMemsetAsync(rep, 0x7F, (size_t)B_SIZE * NBUCKETS * sizeof(int), stream);

    pack_bits<<<dim3(C_SIZE / 4), 256, 0, stream>>>(cache, cbits, C_SIZE);
    pack_bits<<<dim3(B_SIZE / 4), 256, 0, stream>>>(y_true, ybits, B_SIZE);
    compute_rep<<<dim3(C_SIZE / 256), 256, 0, stream>>>(cbits, ybits, rep);
    gather_s<<<dim3(16, B_SIZE), 256, 0, stream>>>(cbits, y_hat, rep, svals);
    finalize<<<1, B_SIZE, 0, stream>>>(rep, svals, (float*)d_out);
}

// Round 2
// 240.672 us; speedup vs baseline: 2.4306x; 2.4306x over previous
//
#include <hip/hip_runtime.h>
#include <stdint.h>

typedef unsigned long long u64;

#define C_SIZE 32768
#define N_SIZE 900
#define B_SIZE 128
#define NWORDS 15      // ceil(900/64): 14 full words + 4 bits
#define WSTRIDE 16     // padded row stride in u64 (128 B, aligned)
#define NBUCKETS 901   // d in [0, 900]
#define IPB 2          // items per block in compute_rep
#define CHUNKS 8       // row chunks in compute_rep
#define ROWS_PER_CHUNK (C_SIZE / CHUNKS)   // 4096

static __device__ inline u64 rfl64(u64 x) {
    uint32_t lo = (uint32_t)__builtin_amdgcn_readfirstlane((int)(uint32_t)x);
    uint32_t hi = (uint32_t)__builtin_amdgcn_readfirstlane((int)(uint32_t)(x >> 32));
    return ((u64)hi << 32) | lo;
}

// ---------------------------------------------------------------------------
// Kernel A: pack 0/1 float rows into bitmasks, one wave per row.
// ---------------------------------------------------------------------------
__global__ __launch_bounds__(256) void pack_bits(const float* __restrict__ src,
                                                 u64* __restrict__ dst, int rows) {
    int wave = (int)((blockIdx.x * blockDim.x + threadIdx.x) >> 6);
    int lane = (int)(threadIdx.x & 63);
    if (wave >= rows) return;
    const float* row = src + (size_t)wave * N_SIZE;
    u64 myword = 0;
#pragma unroll
    for (int w = 0; w < NWORDS; ++w) {
        int j = w * 64 + lane;
        float v = 0.0f;
        if (j < N_SIZE) v = row[j];
        u64 m = __ballot(v != 0.0f);
        if (lane == w) myword = m;
    }
    if (lane < WSTRIDE) dst[(size_t)wave * WSTRIDE + lane] = myword;
}

// ---------------------------------------------------------------------------
// Kernel B (rewritten): hierarchical bucket-argmin.
// Grid (CHUNKS, B_SIZE/IPB). Each block: IPB items, ROWS_PER_CHUNK cache rows.
// y_true bits -> SGPRs (readfirstlane). Row bits -> VGPRs. d via popcount.
// LDS atomicMin into private rep[IPB][901]; flush non-empty buckets with one
// global atomicMin each (~60 per item-chunk instead of 4.19M total).
// ---------------------------------------------------------------------------
__global__ __launch_bounds__(256) void compute_rep(const u64* __restrict__ cbits,
                                                   const u64* __restrict__ ybits,
                                                   int* __restrict__ rep) {
    __shared__ int lrep[IPB][NBUCKETS];
    for (int idx = threadIdx.x; idx < IPB * NBUCKETS; idx += 256)
        ((int*)lrep)[idx] = 0x7fffffff;
    __syncthreads();

    const int item0 = (int)blockIdx.y * IPB;
    const int kbase = (int)blockIdx.x * ROWS_PER_CHUNK;

    // y_true bitmasks, wave-uniform -> SGPRs
    u64 y0[NWORDS], y1[NWORDS];
#pragma unroll
    for (int w = 0; w < NWORDS; ++w) {
        y0[w] = rfl64(ybits[(size_t)item0 * WSTRIDE + w]);
        y1[w] = rfl64(ybits[(size_t)(item0 + 1) * WSTRIDE + w]);
    }

#pragma unroll 1
    for (int i = 0; i < ROWS_PER_CHUNK / 256; ++i) {
        int k = kbase + i * 256 + (int)threadIdx.x;
        const u64* row = cbits + (size_t)k * WSTRIDE;
        u64 ck[NWORDS];
#pragma unroll
        for (int w = 0; w < NWORDS; ++w) ck[w] = row[w];
        int d0 = 0, d1 = 0;
#pragma unroll
        for (int w = 0; w < NWORDS; ++w) {
            d0 += (int)__popcll(ck[w] & y0[w]);
            d1 += (int)__popcll(ck[w] & y1[w]);
        }
        atomicMin(&lrep[0][d0], k);
        atomicMin(&lrep[1][d1], k);
    }
    __syncthreads();

    // flush non-empty buckets
    for (int t = (int)threadIdx.x; t < NBUCKETS; t += 256) {
#pragma unroll
        for (int it = 0; it < IPB; ++it) {
            int v = lrep[it][t];
            if (v != 0x7fffffff) atomicMin(&rep[(item0 + it) * NBUCKETS + t], v);
        }
    }
}

// ---------------------------------------------------------------------------
// Kernel C: masked-sum dot s[rep] = sum_{j: cache[rep][j]==1} y_hat[item][j].
// ---------------------------------------------------------------------------
__global__ __launch_bounds__(256) void gather_s(const u64* __restrict__ cbits,
                                                const float* __restrict__ y_hat,
                                                const int* __restrict__ rep,
                                                float* __restrict__ svals) {
    int item = (int)blockIdx.y;
    int wave_in_item = (int)(blockIdx.x * (blockDim.x >> 6) + (threadIdx.x >> 6)); // 0..63
    int lane = (int)(threadIdx.x & 63);
    const float* yh = y_hat + (size_t)item * N_SIZE;

    for (int t = wave_in_item; t < NBUCKETS; t += 64) {
        int k = rep[item * NBUCKETS + t];   // wave-uniform
        if (k >= C_SIZE) continue;          // empty bucket
        float s = 0.0f;
#pragma unroll
        for (int w = 0; w < NWORDS; ++w) {
            u64 word = cbits[(size_t)k * WSTRIDE + w]; // broadcast
            int j = w * 64 + lane;
            if (j < N_SIZE && ((word >> lane) & 1ull)) s += yh[j];
        }
#pragma unroll
        for (int off = 32; off; off >>= 1) s += __shfl_xor(s, off, 64);
        if (lane == 0) svals[item * NBUCKETS + t] = s;
    }
}

// ---------------------------------------------------------------------------
// Kernel D: per item, find t_max (max present d), best = s[t_max],
// loss = sum_{present t < t_max} relu(s[t]-best) / max(cnt,1); mean over items.
// ---------------------------------------------------------------------------
__global__ void finalize(const int* __restrict__ rep, const float* __restrict__ svals,
                         float* __restrict__ out) {
    __shared__ float red[B_SIZE];
    int i = (int)threadIdx.x; // 0..127
    const int* r = rep + i * NBUCKETS;
    const float* s = svals + i * NBUCKETS;

    int tmax = -1;
    for (int t = NBUCKETS - 1; t >= 0; --t) {
        if (r[t] < C_SIZE) { tmax = t; break; }
    }
    float loss = 0.0f;
    if (tmax >= 0) {
        float best = s[tmax];
        float sum = 0.0f;
        int cnt = 0;
        for (int t = 0; t < tmax; ++t) {
            if (r[t] < C_SIZE) {
                float dd = s[t] - best;
                sum += (dd > 0.0f) ? dd : 0.0f;
                ++cnt;
            }
        }
        loss = sum / (float)((cnt > 1) ? cnt : 1);
    }
    red[i] = loss;
    __syncthreads();
    for (int off = 64; off; off >>= 1) {
        if (i < off) red[i] += red[i + off];
        __syncthreads();
    }
    if (i == 0) out[0] = red[0] / (float)B_SIZE;
}

extern "C" void kernel_launch(void* const* d_in, const int* in_sizes, int n_in,
                              void* d_out, int out_size, void* d_ws, size_t ws_size,
                              hipStream_t stream) {
    const float* y_hat  = (const float*)d_in[0];  // [128, 900]
    const float* y_true = (const float*)d_in[1];  // [128, 900] 0/1
    // d_in[2] = sol_true (unused)
    const float* cache  = (const float*)d_in[3];  // [32768, 900] 0/1

    char* ws = (char*)d_ws;
    u64*   cbits = (u64*)ws;                                   // 4 MiB
    u64*   ybits = (u64*)(ws + 4u * 1024 * 1024);              // 16 KiB
    int*   rep   = (int*)(ws + 4u * 1024 * 1024 + 64 * 1024);  // 461 KiB
    float* svals = (float*)(ws + 4u * 1024 * 1024 + 64 * 1024 + 512 * 1024); // 461 KiB

    // re-init rep buckets each call (0x7F7F7F7F > C_SIZE)
    hipMemsetAsync(rep, 0x7F, (size_t)B_SIZE * NBUCKETS * sizeof(int), stream);

    pack_bits<<<dim3(C_SIZE / 4), 256, 0, stream>>>(cache, cbits, C_SIZE);
    pack_bits<<<dim3(B_SIZE / 4), 256, 0, stream>>>(y_true, ybits, B_SIZE);
    compute_rep<<<dim3(CHUNKS, B_SIZE / IPB), 256, 0, stream>>>(cbits, ybits, rep);
    gather_s<<<dim3(16, B_SIZE), 256, 0, stream>>>(cbits, y_hat, rep, svals);
    finalize<<<1, B_SIZE, 0, stream>>>(rep, svals, (float*)d_out);
}

// Round 3
// 86.531 us; speedup vs baseline: 6.7602x; 2.7813x over previous
//
#include <hip/hip_runtime.h>
#include <stdint.h>

typedef unsigned long long u64;

#define C_SIZE 32768
#define N_SIZE 900
#define B_SIZE 128
#define NWORDS 15      // ceil(900/64): 14 full words + 4 bits
#define WSTRIDE 16     // padded row stride in u64 (128 B, aligned)
#define NBUCKETS 901   // d in [0, 900]
#define IPB 2          // items per block in compute_rep
#define CHUNKS 8       // row chunks in compute_rep
#define ROWS_PER_CHUNK (C_SIZE / CHUNKS)   // 4096

static __device__ inline u64 rfl64(u64 x) {
    uint32_t lo = (uint32_t)__builtin_amdgcn_readfirstlane((int)(uint32_t)x);
    uint32_t hi = (uint32_t)__builtin_amdgcn_readfirstlane((int)(uint32_t)(x >> 32));
    return ((u64)hi << 32) | lo;
}

// ---------------------------------------------------------------------------
// Kernel A: pack 0/1 float rows into bitmasks, one wave per row.
// ---------------------------------------------------------------------------
__global__ __launch_bounds__(256) void pack_bits(const float* __restrict__ src,
                                                 u64* __restrict__ dst, int rows) {
    int wave = (int)((blockIdx.x * blockDim.x + threadIdx.x) >> 6);
    int lane = (int)(threadIdx.x & 63);
    if (wave >= rows) return;
    const float* row = src + (size_t)wave * N_SIZE;
    u64 myword = 0;
#pragma unroll
    for (int w = 0; w < NWORDS; ++w) {
        int j = w * 64 + lane;
        float v = 0.0f;
        if (j < N_SIZE) v = row[j];
        u64 m = __ballot(v != 0.0f);
        if (lane == w) myword = m;
    }
    if (lane < WSTRIDE) dst[(size_t)wave * WSTRIDE + lane] = myword;
}

// ---------------------------------------------------------------------------
// Kernel B: hierarchical bucket-argmin (LDS atomicMin, sparse global flush).
// ---------------------------------------------------------------------------
__global__ __launch_bounds__(256) void compute_rep(const u64* __restrict__ cbits,
                                                   const u64* __restrict__ ybits,
                                                   int* __restrict__ rep) {
    __shared__ int lrep[IPB][NBUCKETS];
    for (int idx = threadIdx.x; idx < IPB * NBUCKETS; idx += 256)
        ((int*)lrep)[idx] = 0x7fffffff;
    __syncthreads();

    const int item0 = (int)blockIdx.y * IPB;
    const int kbase = (int)blockIdx.x * ROWS_PER_CHUNK;

    u64 y0[NWORDS], y1[NWORDS];
#pragma unroll
    for (int w = 0; w < NWORDS; ++w) {
        y0[w] = rfl64(ybits[(size_t)item0 * WSTRIDE + w]);
        y1[w] = rfl64(ybits[(size_t)(item0 + 1) * WSTRIDE + w]);
    }

#pragma unroll 1
    for (int i = 0; i < ROWS_PER_CHUNK / 256; ++i) {
        int k = kbase + i * 256 + (int)threadIdx.x;
        const u64* row = cbits + (size_t)k * WSTRIDE;
        u64 ck[NWORDS];
#pragma unroll
        for (int w = 0; w < NWORDS; ++w) ck[w] = row[w];
        int d0 = 0, d1 = 0;
#pragma unroll
        for (int w = 0; w < NWORDS; ++w) {
            d0 += (int)__popcll(ck[w] & y0[w]);
            d1 += (int)__popcll(ck[w] & y1[w]);
        }
        atomicMin(&lrep[0][d0], k);
        atomicMin(&lrep[1][d1], k);
    }
    __syncthreads();

    for (int t = (int)threadIdx.x; t < NBUCKETS; t += 256) {
#pragma unroll
        for (int it = 0; it < IPB; ++it) {
            int v = lrep[it][t];
            if (v != 0x7fffffff) atomicMin(&rep[(item0 + it) * NBUCKETS + t], v);
        }
    }
}

// ---------------------------------------------------------------------------
// Kernel C: masked-sum dot s[rep] = sum_{j: cache[rep][j]==1} y_hat[item][j].
// ---------------------------------------------------------------------------
__global__ __launch_bounds__(256) void gather_s(const u64* __restrict__ cbits,
                                                const float* __restrict__ y_hat,
                                                const int* __restrict__ rep,
                                                float* __restrict__ svals) {
    int item = (int)blockIdx.y;
    int wave_in_item = (int)(blockIdx.x * (blockDim.x >> 6) + (threadIdx.x >> 6)); // 0..63
    int lane = (int)(threadIdx.x & 63);
    const float* yh = y_hat + (size_t)item * N_SIZE;

    for (int t = wave_in_item; t < NBUCKETS; t += 64) {
        int k = rep[item * NBUCKETS + t];   // wave-uniform
        if (k >= C_SIZE) continue;          // empty bucket
        float s = 0.0f;
#pragma unroll
        for (int w = 0; w < NWORDS; ++w) {
            u64 word = cbits[(size_t)k * WSTRIDE + w]; // broadcast
            int j = w * 64 + lane;
            if (j < N_SIZE && ((word >> lane) & 1ull)) s += yh[j];
        }
#pragma unroll
        for (int off = 32; off; off >>= 1) s += __shfl_xor(s, off, 64);
        if (lane == 0) svals[item * NBUCKETS + t] = s;
    }
}

// ---------------------------------------------------------------------------
// Kernel D1: per-item loss. One block per item, 256 threads strided over
// the 901 buckets; LDS reduce for tmax, then relu-sum + count.
// ---------------------------------------------------------------------------
__global__ __launch_bounds__(256) void finalize_item(const int* __restrict__ rep,
                                                     const float* __restrict__ svals,
                                                     float* __restrict__ loss) {
    int item = (int)blockIdx.x;
    const int* r = rep + item * NBUCKETS;
    const float* s = svals + item * NBUCKETS;
    int tid = (int)threadIdx.x;

    __shared__ int   red_i[256];
    __shared__ float red_f[256];
    __shared__ int   red_c[256];

    // phase 1: tmax = max t with bucket present (strided t is increasing)
    int tmax = -1;
    for (int t = tid; t < NBUCKETS; t += 256)
        if (r[t] < C_SIZE) tmax = t;
    red_i[tid] = tmax;
    __syncthreads();
    for (int off = 128; off; off >>= 1) {
        if (tid < off) red_i[tid] = max(red_i[tid], red_i[tid + off]);
        __syncthreads();
    }
    int tm = red_i[0];
    float best = (tm >= 0) ? s[tm] : 0.0f;

    // phase 2: sum relu(s[t]-best) over present t < tm, count them
    float sum = 0.0f;
    int cnt = 0;
    for (int t = tid; t < tm; t += 256) {
        if (r[t] < C_SIZE) {
            float dd = s[t] - best;
            sum += (dd > 0.0f) ? dd : 0.0f;
            ++cnt;
        }
    }
    red_f[tid] = sum;
    red_c[tid] = cnt;
    __syncthreads();
    for (int off = 128; off; off >>= 1) {
        if (tid < off) { red_f[tid] += red_f[tid + off]; red_c[tid] += red_c[tid + off]; }
        __syncthreads();
    }
    if (tid == 0) loss[item] = red_f[0] / (float)((red_c[0] > 1) ? red_c[0] : 1);
}

// ---------------------------------------------------------------------------
// Kernel D2: mean over 128 per-item losses.
// ---------------------------------------------------------------------------
__global__ void finalize_mean(const float* __restrict__ loss, float* __restrict__ out) {
    __shared__ float red[B_SIZE];
    int i = (int)threadIdx.x;
    red[i] = loss[i];
    __syncthreads();
    for (int off = 64; off; off >>= 1) {
        if (i < off) red[i] += red[i + off];
        __syncthreads();
    }
    if (i == 0) out[0] = red[0] / (float)B_SIZE;
}

extern "C" void kernel_launch(void* const* d_in, const int* in_sizes, int n_in,
                              void* d_out, int out_size, void* d_ws, size_t ws_size,
                              hipStream_t stream) {
    const float* y_hat  = (const float*)d_in[0];  // [128, 900]
    const float* y_true = (const float*)d_in[1];  // [128, 900] 0/1
    // d_in[2] = sol_true (unused)
    const float* cache  = (const float*)d_in[3];  // [32768, 900] 0/1

    char* ws = (char*)d_ws;
    u64*   cbits = (u64*)ws;                                                  // 4 MiB
    u64*   ybits = (u64*)(ws + 4u * 1024 * 1024);                             // 16 KiB
    int*   rep   = (int*)(ws + 4u * 1024 * 1024 + 64 * 1024);                 // 461 KiB
    float* svals = (float*)(ws + 4u * 1024 * 1024 + 64 * 1024 + 512 * 1024);  // 461 KiB
    float* loss  = (float*)(ws + 4u * 1024 * 1024 + 64 * 1024 + 1024 * 1024); // 512 B

    // re-init rep buckets each call (0x7F7F7F7F > C_SIZE)
    hipMemsetAsync(rep, 0x7F, (size_t)B_SIZE * NBUCKETS * sizeof(int), stream);

    pack_bits<<<dim3(C_SIZE / 4), 256, 0, stream>>>(cache, cbits, C_SIZE);
    pack_bits<<<dim3(B_SIZE / 4), 256, 0, stream>>>(y_true, ybits, B_SIZE);
    compute_rep<<<dim3(CHUNKS, B_SIZE / IPB), 256, 0, stream>>>(cbits, ybits, rep);
    gather_s<<<dim3(16, B_SIZE), 256, 0, stream>>>(cbits, y_hat, rep, svals);
    finalize_item<<<dim3(B_SIZE), 256, 0, stream>>>(rep, svals, loss);
    finalize_mean<<<1, B_SIZE, 0, stream>>>(loss, (float*)d_out);
}

// Round 4
// 85.421 us; speedup vs baseline: 6.8480x; 1.0130x over previous
//
#include <hip/hip_runtime.h>
#include <stdint.h>

typedef unsigned long long u64;

#define C_SIZE 32768
#define N_SIZE 900
#define B_SIZE 128
#define NWORDS 15      // ceil(900/64): 14 full words + 4 bits
#define WSTRIDE 16     // padded row stride in u64 (128 B, aligned)
#define NBUCKETS 901   // d in [0, 900]
#define IPB 2          // items per block in compute_rep
#define CHUNKS 8       // row chunks in compute_rep
#define ROWS_PER_CHUNK (C_SIZE / CHUNKS)   // 4096
#define EMPTY 0x7fffffff

static __device__ inline u64 rfl64(u64 x) {
    uint32_t lo = (uint32_t)__builtin_amdgcn_readfirstlane((int)(uint32_t)x);
    uint32_t hi = (uint32_t)__builtin_amdgcn_readfirstlane((int)(uint32_t)(x >> 32));
    return ((u64)hi << 32) | lo;
}

// ---------------------------------------------------------------------------
// Kernel A: pack 0/1 float rows into bitmasks, one wave per row.
// Handles BOTH cache (rows [0, C_SIZE)) and y_true (rows [C_SIZE, C_SIZE+B_SIZE)).
// ---------------------------------------------------------------------------
__global__ __launch_bounds__(256) void pack_bits_all(const float* __restrict__ cache,
                                                     const float* __restrict__ y_true,
                                                     u64* __restrict__ cbits,
                                                     u64* __restrict__ ybits) {
    int wave = (int)((blockIdx.x * blockDim.x + threadIdx.x) >> 6);
    int lane = (int)(threadIdx.x & 63);
    const float* row;
    u64* dst;
    if (wave < C_SIZE) {
        row = cache + (size_t)wave * N_SIZE;
        dst = cbits + (size_t)wave * WSTRIDE;
    } else if (wave < C_SIZE + B_SIZE) {
        int r = wave - C_SIZE;
        row = y_true + (size_t)r * N_SIZE;
        dst = ybits + (size_t)r * WSTRIDE;
    } else {
        return;
    }
    u64 myword = 0;
#pragma unroll
    for (int w = 0; w < NWORDS; ++w) {
        int j = w * 64 + lane;
        float v = 0.0f;
        if (j < N_SIZE) v = row[j];
        u64 m = __ballot(v != 0.0f);
        if (lane == w) myword = m;
    }
    if (lane < WSTRIDE) dst[lane] = myword;
}

// ---------------------------------------------------------------------------
// Kernel B: per-(chunk, item-pair) bucket-argmin into a PRIVATE slice of repc.
// LDS atomicMin only; full 901-entry table written out coalesced (incl. EMPTY)
// so no global init/memset is ever needed.
// repc layout: [CHUNKS][B_SIZE][NBUCKETS]
// ---------------------------------------------------------------------------
__global__ __launch_bounds__(256) void compute_rep(const u64* __restrict__ cbits,
                                                   const u64* __restrict__ ybits,
                                                   int* __restrict__ repc) {
    __shared__ int lrep[IPB][NBUCKETS];
    for (int idx = threadIdx.x; idx < IPB * NBUCKETS; idx += 256)
        ((int*)lrep)[idx] = EMPTY;
    __syncthreads();

    const int item0 = (int)blockIdx.y * IPB;
    const int kbase = (int)blockIdx.x * ROWS_PER_CHUNK;

    u64 y0[NWORDS], y1[NWORDS];
#pragma unroll
    for (int w = 0; w < NWORDS; ++w) {
        y0[w] = rfl64(ybits[(size_t)item0 * WSTRIDE + w]);
        y1[w] = rfl64(ybits[(size_t)(item0 + 1) * WSTRIDE + w]);
    }

#pragma unroll 1
    for (int i = 0; i < ROWS_PER_CHUNK / 256; ++i) {
        int k = kbase + i * 256 + (int)threadIdx.x;
        const u64* row = cbits + (size_t)k * WSTRIDE;
        u64 ck[NWORDS];
#pragma unroll
        for (int w = 0; w < NWORDS; ++w) ck[w] = row[w];
        int d0 = 0, d1 = 0;
#pragma unroll
        for (int w = 0; w < NWORDS; ++w) {
            d0 += (int)__popcll(ck[w] & y0[w]);
            d1 += (int)__popcll(ck[w] & y1[w]);
        }
        atomicMin(&lrep[0][d0], k);
        atomicMin(&lrep[1][d1], k);
    }
    __syncthreads();

    for (int t = (int)threadIdx.x; t < NBUCKETS; t += 256) {
#pragma unroll
        for (int it = 0; it < IPB; ++it) {
            repc[((size_t)blockIdx.x * B_SIZE + (item0 + it)) * NBUCKETS + t] = lrep[it][t];
        }
    }
}

// ---------------------------------------------------------------------------
// Kernel C: fold the 8-way chunk-min (wave-broadcast L2 loads), write combined
// rep for finalize, and compute masked-sum dot s[rep] where present.
// ---------------------------------------------------------------------------
__global__ __launch_bounds__(256) void gather_s(const u64* __restrict__ cbits,
                                                const float* __restrict__ y_hat,
                                                const int* __restrict__ repc,
                                                int* __restrict__ rep,
                                                float* __restrict__ svals) {
    int item = (int)blockIdx.y;
    int wave_in_item = (int)(blockIdx.x * (blockDim.x >> 6) + (threadIdx.x >> 6)); // 0..63
    int lane = (int)(threadIdx.x & 63);
    const float* yh = y_hat + (size_t)item * N_SIZE;

    for (int t = wave_in_item; t < NBUCKETS; t += 64) {
        int k = EMPTY;
#pragma unroll
        for (int c = 0; c < CHUNKS; ++c) {
            int v = repc[((size_t)c * B_SIZE + item) * NBUCKETS + t]; // broadcast
            k = min(k, v);
        }
        if (lane == 0) rep[item * NBUCKETS + t] = k;
        if (k >= C_SIZE) continue;          // empty bucket
        float s = 0.0f;
#pragma unroll
        for (int w = 0; w < NWORDS; ++w) {
            u64 word = cbits[(size_t)k * WSTRIDE + w]; // broadcast
            int j = w * 64 + lane;
            if (j < N_SIZE && ((word >> lane) & 1ull)) s += yh[j];
        }
#pragma unroll
        for (int off = 32; off; off >>= 1) s += __shfl_xor(s, off, 64);
        if (lane == 0) svals[item * NBUCKETS + t] = s;
    }
}

// ---------------------------------------------------------------------------
// Kernel D1: per-item loss. One block per item, 256 threads strided over
// the 901 buckets; LDS reduce for tmax, then relu-sum + count.
// ---------------------------------------------------------------------------
__global__ __launch_bounds__(256) void finalize_item(const int* __restrict__ rep,
                                                     const float* __restrict__ svals,
                                                     float* __restrict__ loss) {
    int item = (int)blockIdx.x;
    const int* r = rep + item * NBUCKETS;
    const float* s = svals + item * NBUCKETS;
    int tid = (int)threadIdx.x;

    __shared__ int   red_i[256];
    __shared__ float red_f[256];
    __shared__ int   red_c[256];

    int tmax = -1;
    for (int t = tid; t < NBUCKETS; t += 256)
        if (r[t] < C_SIZE) tmax = t;
    red_i[tid] = tmax;
    __syncthreads();
    for (int off = 128; off; off >>= 1) {
        if (tid < off) red_i[tid] = max(red_i[tid], red_i[tid + off]);
        __syncthreads();
    }
    int tm = red_i[0];
    float best = (tm >= 0) ? s[tm] : 0.0f;

    float sum = 0.0f;
    int cnt = 0;
    for (int t = tid; t < tm; t += 256) {
        if (r[t] < C_SIZE) {
            float dd = s[t] - best;
            sum += (dd > 0.0f) ? dd : 0.0f;
            ++cnt;
        }
    }
    red_f[tid] = sum;
    red_c[tid] = cnt;
    __syncthreads();
    for (int off = 128; off; off >>= 1) {
        if (tid < off) { red_f[tid] += red_f[tid + off]; red_c[tid] += red_c[tid + off]; }
        __syncthreads();
    }
    if (tid == 0) loss[item] = red_f[0] / (float)((red_c[0] > 1) ? red_c[0] : 1);
}

// ---------------------------------------------------------------------------
// Kernel D2: mean over 128 per-item losses.
// ---------------------------------------------------------------------------
__global__ void finalize_mean(const float* __restrict__ loss, float* __restrict__ out) {
    __shared__ float red[B_SIZE];
    int i = (int)threadIdx.x;
    red[i] = loss[i];
    __syncthreads();
    for (int off = 64; off; off >>= 1) {
        if (i < off) red[i] += red[i + off];
        __syncthreads();
    }
    if (i == 0) out[0] = red[0] / (float)B_SIZE;
}

extern "C" void kernel_launch(void* const* d_in, const int* in_sizes, int n_in,
                              void* d_out, int out_size, void* d_ws, size_t ws_size,
                              hipStream_t stream) {
    const float* y_hat  = (const float*)d_in[0];  // [128, 900]
    const float* y_true = (const float*)d_in[1];  // [128, 900] 0/1
    // d_in[2] = sol_true (unused)
    const float* cache  = (const float*)d_in[3];  // [32768, 900] 0/1

    char* ws = (char*)d_ws;
    u64*   cbits = (u64*)ws;                                   // 4 MiB
    u64*   ybits = (u64*)(ws + (4u << 20));                    // 16 KiB
    int*   repc  = (int*)(ws + (4u << 20) + (64u << 10));      // 8*128*901*4 = 3.52 MiB
    int*   rep   = (int*)(ws + (8u << 20));                    // 461 KiB
    float* svals = (float*)(ws + (8u << 20) + (512u << 10));   // 461 KiB
    float* loss  = (float*)(ws + (9u << 20));                  // 512 B

    int total_waves = C_SIZE + B_SIZE;                 // 32896
    int pack_blocks = (total_waves + 3) / 4;           // 4 waves per 256-thr block
    pack_bits_all<<<dim3(pack_blocks), 256, 0, stream>>>(cache, y_true, cbits, ybits);
    compute_rep<<<dim3(CHUNKS, B_SIZE / IPB), 256, 0, stream>>>(cbits, ybits, repc);
    gather_s<<<dim3(16, B_SIZE), 256, 0, stream>>>(cbits, y_hat, repc, rep, svals);
    finalize_item<<<dim3(B_SIZE), 256, 0, stream>>>(rep, svals, loss);
    finalize_mean<<<1, B_SIZE, 0, stream>>>(loss, (float*)d_out);
}